// Round 1
// baseline (40329.324 us; speedup 1.0000x reference)
//
#include <hip/hip_runtime.h>
#include <math.h>

// MultilayerLSTM: B=16, S=512, D_IN=512, D_H=1024, D_OUT=2, VOCAB=32000
// Round 0: all-f32 correctness-first baseline.
// Structure:
//   zero_cnt -> embed -> xproj(l0) -> lstm_rec(l0) -> xproj(l1) -> lstm_rec(l1) -> head
// lstm_rec is a persistent 256-block kernel with a hand-rolled grid barrier
// (device/agent-scope atomics + fences; 256 blocks always co-resident:
//  LDS 17.7KB, <=128 VGPR -> capacity ~8 blocks/CU * 256 CUs >> 256).

#define BB   16
#define SLEN 512
#define DIN  512
#define DH   1024
// rows = BB*SLEN = 8192

// ---------------- zero counters ----------------
__global__ void zero_cnt_kernel(unsigned* cnt) {
  if (threadIdx.x < 8) cnt[threadIdx.x] = 0;
}

// ---------------- embedding gather ----------------
__global__ __launch_bounds__(256) void embed_kernel(const int* __restrict__ tokens,
                                                    const float* __restrict__ emb,
                                                    float* __restrict__ x0) {
  int idx = blockIdx.x * 256 + threadIdx.x;  // over 8192*128 float4s
  int r = idx >> 7, d4 = idx & 127;
  int tok = tokens[r];
  const float4* src = (const float4*)emb + (((size_t)tok) << 7) + d4;
  ((float4*)x0)[(((size_t)r) << 7) + d4] = *src;
}

// ---------------- xproj GEMM: C[M][4096] = A[M][K] @ W_g[K][1024] + b_g ----------------
// 128x128 tile, 256 threads, 8x8 microtile. Gate selected per 128-col block (1024%128==0).
__global__ __launch_bounds__(256) void xproj_kernel(
    const float* __restrict__ A, int K,
    const float* __restrict__ Wi, const float* __restrict__ Wf,
    const float* __restrict__ Wg, const float* __restrict__ Wo,
    const float* __restrict__ bi, const float* __restrict__ bf,
    const float* __restrict__ bg, const float* __restrict__ bo,
    float* __restrict__ Cout)
{
  __shared__ float As[8][128];
  __shared__ float Bs[8][128];
  const int tid = threadIdx.x;
  const int bn = blockIdx.x;   // 0..31
  const int bm = blockIdx.y;   // 0..63
  const int m0 = bm * 128;
  const int n0 = bn * 128;
  const int g = n0 >> 10;
  const float* W    = (g == 0) ? Wi : (g == 1) ? Wf : (g == 2) ? Wg : Wo;
  const float* bias = (g == 0) ? bi : (g == 1) ? bf : (g == 2) ? bg : bo;
  const int col0 = n0 & 1023;
  const int tx = tid & 15, ty = tid >> 4;
  const int lr = tid >> 1, lh = tid & 1;          // A-tile loader
  const int lk = tid >> 5, ln = (tid & 31) << 2;  // B-tile loader

  float acc[8][8];
#pragma unroll
  for (int i = 0; i < 8; ++i)
#pragma unroll
    for (int j = 0; j < 8; ++j) acc[i][j] = 0.f;

  for (int k0 = 0; k0 < K; k0 += 8) {
    float4 av = *(const float4*)(A + (size_t)(m0 + lr) * K + k0 + lh * 4);
    float4 bv = *(const float4*)(W + (size_t)(k0 + lk) * 1024 + col0 + ln);
    As[lh * 4 + 0][lr] = av.x;
    As[lh * 4 + 1][lr] = av.y;
    As[lh * 4 + 2][lr] = av.z;
    As[lh * 4 + 3][lr] = av.w;
    *(float4*)&Bs[lk][ln] = bv;
    __syncthreads();
#pragma unroll
    for (int p = 0; p < 8; ++p) {
      float a[8], b[8];
      *(float4*)&a[0] = *(const float4*)&As[p][ty * 8];
      *(float4*)&a[4] = *(const float4*)&As[p][ty * 8 + 4];
      *(float4*)&b[0] = *(const float4*)&Bs[p][tx * 4];
      *(float4*)&b[4] = *(const float4*)&Bs[p][64 + tx * 4];
#pragma unroll
      for (int i = 0; i < 8; ++i)
#pragma unroll
        for (int j = 0; j < 8; ++j) acc[i][j] += a[i] * b[j];
    }
    __syncthreads();
  }
  float4 bA = *(const float4*)(bias + col0 + tx * 4);
  float4 bB = *(const float4*)(bias + col0 + 64 + tx * 4);
#pragma unroll
  for (int i = 0; i < 8; ++i) {
    int m = m0 + ty * 8 + i;
    float* crow = Cout + (((size_t)m) << 12) + n0;
    float4 o1 = make_float4(acc[i][0] + bA.x, acc[i][1] + bA.y, acc[i][2] + bA.z, acc[i][3] + bA.w);
    float4 o2 = make_float4(acc[i][4] + bB.x, acc[i][5] + bB.y, acc[i][6] + bB.z, acc[i][7] + bB.w);
    *(float4*)(crow + tx * 4) = o1;
    *(float4*)(crow + 64 + tx * 4) = o2;
  }
}

// ---------------- persistent LSTM recurrence ----------------
// 256 blocks x 256 threads. Block bi owns hidden cols c0..c0+3 for all 4 gates.
// Per step: gates[b][g][c] = xp[b,t,g*1024+c] + sum_k H[b][k]*W_g[D+k][c]
// W read from global (block slice 64KB, L2-resident per XCD); H from global (L3).
// Thread tile: 4b x 4gates(via j-group) x 4k; 16-way k-split; LDS reduce.
#define ROWFMA(i, hv)                                              \
  acc##i##0 += hv.x * w0.x + hv.y * w1.x + hv.z * w2.x + hv.w * w3.x; \
  acc##i##1 += hv.x * w0.y + hv.y * w1.y + hv.z * w2.y + hv.w * w3.y; \
  acc##i##2 += hv.x * w0.z + hv.y * w1.z + hv.z * w2.z + hv.w * w3.z; \
  acc##i##3 += hv.x * w0.w + hv.y * w1.w + hv.z * w2.w + hv.w * w3.w;

__global__ __launch_bounds__(256) void lstm_rec_kernel(
    const float* __restrict__ xp,
    const float* __restrict__ Wi, const float* __restrict__ Wf,
    const float* __restrict__ Wg, const float* __restrict__ Wo,
    int D,
    float* __restrict__ hseq,
    unsigned* __restrict__ cnt)
{
  __shared__ float Part[16 * 260];  // [ks][b*16 + g*4 + c], stride 260 vs bank conflicts
  __shared__ float Pre[256];        // reduced preacts [b*16 + g*4 + c]
  const int tid = threadIdx.x;
  const int bi = blockIdx.x;
  const int c0 = bi << 2;
  const int ks = tid >> 4;        // 0..15: k-slice [ks*64, ks*64+64)
  const int tb = (tid >> 2) & 3;  // batch group: b = tb*4 + i
  const int tj = tid & 3;         // gate
  const float* Wsel = (tj == 0) ? Wi : (tj == 1) ? Wf : (tj == 2) ? Wg : Wo;
  const float* wbase = Wsel + (size_t)(D + ks * 64) * 1024 + c0;
  const int sb = tid >> 2;  // stage-2 (tid<64): batch
  const int sc = tid & 3;   // stage-2: column
  float Creg = 0.f;

  for (int t = 0; t < SLEN; ++t) {
    float acc00 = 0, acc01 = 0, acc02 = 0, acc03 = 0;
    float acc10 = 0, acc11 = 0, acc12 = 0, acc13 = 0;
    float acc20 = 0, acc21 = 0, acc22 = 0, acc23 = 0;
    float acc30 = 0, acc31 = 0, acc32 = 0, acc33 = 0;
    if (t > 0) {
      const float* h0p = hseq + (((size_t)((tb * 4 + 0) * SLEN + t - 1)) << 10) + (ks << 6);
      const float* h1p = h0p + (((size_t)SLEN) << 10);
      const float* h2p = h1p + (((size_t)SLEN) << 10);
      const float* h3p = h2p + (((size_t)SLEN) << 10);
#pragma unroll 4
      for (int kk = 0; kk < 64; kk += 4) {
        float4 w0 = *(const float4*)(wbase + (size_t)(kk + 0) * 1024);
        float4 w1 = *(const float4*)(wbase + (size_t)(kk + 1) * 1024);
        float4 w2 = *(const float4*)(wbase + (size_t)(kk + 2) * 1024);
        float4 w3 = *(const float4*)(wbase + (size_t)(kk + 3) * 1024);
        float4 h0v = *(const float4*)(h0p + kk);
        float4 h1v = *(const float4*)(h1p + kk);
        float4 h2v = *(const float4*)(h2p + kk);
        float4 h3v = *(const float4*)(h3p + kk);
        ROWFMA(0, h0v)
        ROWFMA(1, h1v)
        ROWFMA(2, h2v)
        ROWFMA(3, h3v)
      }
    }
    // write partials (float4 per batch row)
    *(float4*)&Part[ks * 260 + (tb * 4 + 0) * 16 + tj * 4] = make_float4(acc00, acc01, acc02, acc03);
    *(float4*)&Part[ks * 260 + (tb * 4 + 1) * 16 + tj * 4] = make_float4(acc10, acc11, acc12, acc13);
    *(float4*)&Part[ks * 260 + (tb * 4 + 2) * 16 + tj * 4] = make_float4(acc20, acc21, acc22, acc23);
    *(float4*)&Part[ks * 260 + (tb * 4 + 3) * 16 + tj * 4] = make_float4(acc30, acc31, acc32, acc33);
    __syncthreads();
    // stage 1: reduce k-splits, add xp (+bias already folded in xproj)
    {
      const int jb = tid >> 4, jj = tid & 15, jg = jj >> 2, jc = jj & 3;
      float s = xp[(((size_t)(jb * SLEN + t)) << 12) + (jg << 10) + c0 + jc];
#pragma unroll
      for (int q = 0; q < 16; ++q) s += Part[q * 260 + tid];
      Pre[tid] = s;
    }
    __syncthreads();
    // stage 2: cell update (64 threads own C in registers)
    if (tid < 64) {
      float pI = Pre[sb * 16 + 0 + sc];
      float pF = Pre[sb * 16 + 4 + sc];
      float pG = Pre[sb * 16 + 8 + sc];
      float pO = Pre[sb * 16 + 12 + sc];
      float gI = 1.f / (1.f + __expf(-pI));
      float gF = 1.f / (1.f + __expf(-pF));
      float gG = tanhf(pG);
      float gO = 1.f / (1.f + __expf(-pO));
      Creg = gF * Creg + gI * gG;
      hseq[(((size_t)(sb * SLEN + t)) << 10) + c0 + sc] = gO * tanhf(Creg);
    }
    __syncthreads();
    // grid barrier (skip after last step; kernel boundary flushes)
    if (t + 1 < SLEN) {
      if (tid == 0) {
        __builtin_amdgcn_fence(__ATOMIC_RELEASE, "agent");
        __hip_atomic_fetch_add(cnt, 1u, __ATOMIC_RELAXED, __HIP_MEMORY_SCOPE_AGENT);
        const unsigned target = 256u * (unsigned)(t + 1);
        while (__hip_atomic_load(cnt, __ATOMIC_RELAXED, __HIP_MEMORY_SCOPE_AGENT) < target) {
          __builtin_amdgcn_s_sleep(2);
        }
        __builtin_amdgcn_fence(__ATOMIC_ACQUIRE, "agent");
      }
      __syncthreads();
    }
  }
}

// ---------------- FC head + log_softmax (D_OUT=2) ----------------
__global__ __launch_bounds__(256) void head_kernel(const float* __restrict__ h,
                                                   const float* __restrict__ Wfc,
                                                   const float* __restrict__ bfc,
                                                   float* __restrict__ out)
{
  const int lane = threadIdx.x & 63;
  const int row = blockIdx.x * 4 + (threadIdx.x >> 6);
  const float* hr = h + (((size_t)row) << 10);
  float s0 = 0.f, s1 = 0.f;
#pragma unroll
  for (int i = 0; i < 16; ++i) {
    int k = lane + i * 64;
    float hv = hr[k];
    float2 w = *(const float2*)(Wfc + 2 * k);
    s0 += hv * w.x;
    s1 += hv * w.y;
  }
#pragma unroll
  for (int off = 32; off > 0; off >>= 1) {
    s0 += __shfl_down(s0, off);
    s1 += __shfl_down(s1, off);
  }
  if (lane == 0) {
    s0 += bfc[0];
    s1 += bfc[1];
    float m = fmaxf(s0, s1);
    float lse = m + logf(expf(s0 - m) + expf(s1 - m));
    out[((size_t)row << 1) + 0] = s0 - lse;
    out[((size_t)row << 1) + 1] = s1 - lse;
  }
}

extern "C" void kernel_launch(void* const* d_in, const int* in_sizes, int n_in,
                              void* d_out, int out_size, void* d_ws, size_t ws_size,
                              hipStream_t stream)
{
  const int*   tokens = (const int*)d_in[0];
  const float* emb = (const float*)d_in[1];
  const float* W0i = (const float*)d_in[2];
  const float* b0i = (const float*)d_in[3];
  const float* W0f = (const float*)d_in[4];
  const float* b0f = (const float*)d_in[5];
  const float* W0g = (const float*)d_in[6];
  const float* b0g = (const float*)d_in[7];
  const float* W0o = (const float*)d_in[8];
  const float* b0o = (const float*)d_in[9];
  const float* W1i = (const float*)d_in[10];
  const float* b1i = (const float*)d_in[11];
  const float* W1f = (const float*)d_in[12];
  const float* b1f = (const float*)d_in[13];
  const float* W1g = (const float*)d_in[14];
  const float* b1g = (const float*)d_in[15];
  const float* W1o = (const float*)d_in[16];
  const float* b1o = (const float*)d_in[17];
  const float* Wfc = (const float*)d_in[18];
  const float* bfc = (const float*)d_in[19];
  float* out = (float*)d_out;

  float* ws = (float*)d_ws;
  float* x0 = ws;                               // 8192*512
  float* h0 = x0 + (size_t)8192 * 512;          // 8192*1024 (reused as h1)
  float* xp = h0 + (size_t)8192 * 1024;         // 8192*4096 (reused for both layers)
  unsigned* cnt = (unsigned*)(xp + (size_t)8192 * 4096);  // 8 u32

  zero_cnt_kernel<<<1, 64, 0, stream>>>(cnt);
  embed_kernel<<<4096, 256, 0, stream>>>(tokens, emb, x0);
  xproj_kernel<<<dim3(32, 64), 256, 0, stream>>>(x0, 512,  W0i, W0f, W0g, W0o,
                                                 b0i, b0f, b0g, b0o, xp);
  lstm_rec_kernel<<<256, 256, 0, stream>>>(xp, W0i, W0f, W0g, W0o, 512, h0, cnt);
  xproj_kernel<<<dim3(32, 64), 256, 0, stream>>>(h0, 1024, W1i, W1f, W1g, W1o,
                                                 b1i, b1f, b1g, b1o, xp);
  lstm_rec_kernel<<<256, 256, 0, stream>>>(xp, W1i, W1f, W1g, W1o, 1024, h0, cnt + 1);
  head_kernel<<<2048, 256, 0, stream>>>(h0, Wfc, bfc, out);
}

// Round 2
// 19256.757 us; speedup vs baseline: 2.0943x; 2.0943x over previous
//
#include <hip/hip_runtime.h>
#include <math.h>

// MultilayerLSTM: B=16, S=512, D_IN=512, D_H=1024, D_OUT=2, VOCAB=32000
// Round 1: recurrence with PERSISTENT W IN REGISTERS (immune to the per-step
// L2 invalidation done by the grid-barrier acquire fence), in-wave shfl_xor
// partial reduction, H read from global per step.
//   zero_cnt -> embed -> xproj(l0) -> lstm_rec(l0) -> xproj(l1) -> lstm_rec(l1) -> head

#define BB   16
#define SLEN 512
#define DIN  512
#define DH   1024

// ---------------- zero counters ----------------
__global__ void zero_cnt_kernel(unsigned* cnt) {
  if (threadIdx.x < 8) cnt[threadIdx.x] = 0;
}

// ---------------- embedding gather ----------------
__global__ __launch_bounds__(256) void embed_kernel(const int* __restrict__ tokens,
                                                    const float* __restrict__ emb,
                                                    float* __restrict__ x0) {
  int idx = blockIdx.x * 256 + threadIdx.x;  // over 8192*128 float4s
  int r = idx >> 7, d4 = idx & 127;
  int tok = tokens[r];
  const float4* src = (const float4*)emb + (((size_t)tok) << 7) + d4;
  ((float4*)x0)[(((size_t)r) << 7) + d4] = *src;
}

// ---------------- xproj GEMM: C[M][4096] = A[M][K] @ W_g[K][1024] + b_g ----------------
__global__ __launch_bounds__(256) void xproj_kernel(
    const float* __restrict__ A, int K,
    const float* __restrict__ Wi, const float* __restrict__ Wf,
    const float* __restrict__ Wg, const float* __restrict__ Wo,
    const float* __restrict__ bi, const float* __restrict__ bf,
    const float* __restrict__ bg, const float* __restrict__ bo,
    float* __restrict__ Cout)
{
  __shared__ float As[8][128];
  __shared__ float Bs[8][128];
  const int tid = threadIdx.x;
  const int bn = blockIdx.x;   // 0..31
  const int bm = blockIdx.y;   // 0..63
  const int m0 = bm * 128;
  const int n0 = bn * 128;
  const int g = n0 >> 10;
  const float* W    = (g == 0) ? Wi : (g == 1) ? Wf : (g == 2) ? Wg : Wo;
  const float* bias = (g == 0) ? bi : (g == 1) ? bf : (g == 2) ? bg : bo;
  const int col0 = n0 & 1023;
  const int tx = tid & 15, ty = tid >> 4;
  const int lr = tid >> 1, lh = tid & 1;          // A-tile loader
  const int lk = tid >> 5, ln = (tid & 31) << 2;  // B-tile loader

  float acc[8][8];
#pragma unroll
  for (int i = 0; i < 8; ++i)
#pragma unroll
    for (int j = 0; j < 8; ++j) acc[i][j] = 0.f;

  for (int k0 = 0; k0 < K; k0 += 8) {
    float4 av = *(const float4*)(A + (size_t)(m0 + lr) * K + k0 + lh * 4);
    float4 bv = *(const float4*)(W + (size_t)(k0 + lk) * 1024 + col0 + ln);
    As[lh * 4 + 0][lr] = av.x;
    As[lh * 4 + 1][lr] = av.y;
    As[lh * 4 + 2][lr] = av.z;
    As[lh * 4 + 3][lr] = av.w;
    *(float4*)&Bs[lk][ln] = bv;
    __syncthreads();
#pragma unroll
    for (int p = 0; p < 8; ++p) {
      float a[8], b[8];
      *(float4*)&a[0] = *(const float4*)&As[p][ty * 8];
      *(float4*)&a[4] = *(const float4*)&As[p][ty * 8 + 4];
      *(float4*)&b[0] = *(const float4*)&Bs[p][tx * 4];
      *(float4*)&b[4] = *(const float4*)&Bs[p][64 + tx * 4];
#pragma unroll
      for (int i = 0; i < 8; ++i)
#pragma unroll
        for (int j = 0; j < 8; ++j) acc[i][j] += a[i] * b[j];
    }
    __syncthreads();
  }
  float4 bA = *(const float4*)(bias + col0 + tx * 4);
  float4 bB = *(const float4*)(bias + col0 + 64 + tx * 4);
#pragma unroll
  for (int i = 0; i < 8; ++i) {
    int m = m0 + ty * 8 + i;
    float* crow = Cout + (((size_t)m) << 12) + n0;
    float4 o1 = make_float4(acc[i][0] + bA.x, acc[i][1] + bA.y, acc[i][2] + bA.z, acc[i][3] + bA.w);
    float4 o2 = make_float4(acc[i][4] + bB.x, acc[i][5] + bB.y, acc[i][6] + bB.z, acc[i][7] + bB.w);
    *(float4*)(crow + tx * 4) = o1;
    *(float4*)(crow + 64 + tx * 4) = o2;
  }
}

// ---------------- persistent LSTM recurrence, W in registers ----------------
// 256 blocks x 256 threads. Block owns hidden cols c0..c0+3 for all 4 gates.
// Thread layout: g = tid>>6 (gate == wave), ks = tid&63 (k-slice of 16 k).
// Each thread keeps W[g][D+ks*16 .. +15][c0..c0+3] = 16 float4 in VGPRs for
// the whole sequence. Per step: 16 batches x 16 k x 4 cols = 1024 FMA.
// Partial reduction: shfl_xor 1,2 within wave (k-split 64 -> 16), then LDS.
#define FMA4(accv, s, wv)   \
  accv.x += (s) * (wv).x;   \
  accv.y += (s) * (wv).y;   \
  accv.z += (s) * (wv).z;   \
  accv.w += (s) * (wv).w;

__global__ __launch_bounds__(256, 1) void lstm_rec_kernel(
    const float* __restrict__ xp,
    const float* __restrict__ Wi, const float* __restrict__ Wf,
    const float* __restrict__ Wg, const float* __restrict__ Wo,
    int D,
    float* __restrict__ hseq,
    unsigned* __restrict__ cnt)
{
  __shared__ float Part[16 * 260];
  __shared__ float Pre[256];
  const int tid = threadIdx.x;
  const int c0 = blockIdx.x << 2;
  const int g  = tid >> 6;   // gate (wave id)
  const int ks = tid & 63;   // k-slice: k in [ks*16, ks*16+16)
  const float* Wsel = (g == 0) ? Wi : (g == 1) ? Wf : (g == 2) ? Wg : Wo;

  // persistent weights: 16 float4 = 64 VGPRs
  float4 w4[16];
#pragma unroll
  for (int kk = 0; kk < 16; ++kk)
    w4[kk] = *(const float4*)(Wsel + (size_t)(D + ks * 16 + kk) * 1024 + c0);

  const int rb = tid >> 4, rg = (tid >> 2) & 3, rc = tid & 3;  // reduce map
  const int sb = tid >> 2, sc = tid & 3;                       // cell map
  float Creg = 0.f;

  for (int t = 0; t < SLEN; ++t) {
    // prefetch this thread's xp element (used in reduce phase)
    float xv = xp[(((size_t)(rb * SLEN + t)) << 12) + (rg << 10) + c0 + rc];

    float4 acc4[16];
#pragma unroll
    for (int b = 0; b < 16; ++b) acc4[b] = make_float4(0.f, 0.f, 0.f, 0.f);

    if (t > 0) {
#pragma unroll
      for (int b = 0; b < 16; ++b) {
        const float4* hp = (const float4*)(hseq + (((size_t)(b * SLEN + t - 1)) << 10) + (ks << 4));
        float hs[16];
        *(float4*)&hs[0]  = hp[0];
        *(float4*)&hs[4]  = hp[1];
        *(float4*)&hs[8]  = hp[2];
        *(float4*)&hs[12] = hp[3];
#pragma unroll
        for (int kk = 0; kk < 16; ++kk) { FMA4(acc4[b], hs[kk], w4[kk]) }
      }
    }

    // in-wave reduce: fold k-slices ks^1 then ks^2 (64 -> 16 partials)
#pragma unroll
    for (int b = 0; b < 16; ++b) {
      acc4[b].x += __shfl_xor(acc4[b].x, 1, 64);
      acc4[b].y += __shfl_xor(acc4[b].y, 1, 64);
      acc4[b].z += __shfl_xor(acc4[b].z, 1, 64);
      acc4[b].w += __shfl_xor(acc4[b].w, 1, 64);
    }
#pragma unroll
    for (int b = 0; b < 16; ++b) {
      acc4[b].x += __shfl_xor(acc4[b].x, 2, 64);
      acc4[b].y += __shfl_xor(acc4[b].y, 2, 64);
      acc4[b].z += __shfl_xor(acc4[b].z, 2, 64);
      acc4[b].w += __shfl_xor(acc4[b].w, 2, 64);
    }
    if ((ks & 3) == 0) {
#pragma unroll
      for (int b = 0; b < 16; ++b)
        *(float4*)&Part[(ks >> 2) * 260 + b * 16 + g * 4] = acc4[b];
    }
    __syncthreads();

    // stage 1: sum 16 k-groups + xp (bias folded into xproj)
    {
      float s = xv;
#pragma unroll
      for (int q = 0; q < 16; ++q) s += Part[q * 260 + tid];
      Pre[tid] = s;
    }
    __syncthreads();

    // stage 2: cell update; 64 threads own C in registers
    if (tid < 64) {
      float pI = Pre[sb * 16 + 0 + sc];
      float pF = Pre[sb * 16 + 4 + sc];
      float pG = Pre[sb * 16 + 8 + sc];
      float pO = Pre[sb * 16 + 12 + sc];
      float gI = 1.f / (1.f + __expf(-pI));
      float gF = 1.f / (1.f + __expf(-pF));
      float gG = tanhf(pG);
      float gO = 1.f / (1.f + __expf(-pO));
      Creg = gF * Creg + gI * gG;
      hseq[(((size_t)(sb * SLEN + t)) << 10) + c0 + sc] = gO * tanhf(Creg);
    }
    __syncthreads();

    // grid barrier (skip after last step; kernel boundary flushes)
    if (t + 1 < SLEN) {
      if (tid == 0) {
        __builtin_amdgcn_fence(__ATOMIC_RELEASE, "agent");
        __hip_atomic_fetch_add(cnt, 1u, __ATOMIC_RELAXED, __HIP_MEMORY_SCOPE_AGENT);
        const unsigned target = 256u * (unsigned)(t + 1);
        while (__hip_atomic_load(cnt, __ATOMIC_RELAXED, __HIP_MEMORY_SCOPE_AGENT) < target) {
          __builtin_amdgcn_s_sleep(1);
        }
        __builtin_amdgcn_fence(__ATOMIC_ACQUIRE, "agent");
      }
      __syncthreads();
    }
  }
}

// ---------------- FC head + log_softmax (D_OUT=2) ----------------
__global__ __launch_bounds__(256) void head_kernel(const float* __restrict__ h,
                                                   const float* __restrict__ Wfc,
                                                   const float* __restrict__ bfc,
                                                   float* __restrict__ out)
{
  const int lane = threadIdx.x & 63;
  const int row = blockIdx.x * 4 + (threadIdx.x >> 6);
  const float* hr = h + (((size_t)row) << 10);
  float s0 = 0.f, s1 = 0.f;
#pragma unroll
  for (int i = 0; i < 16; ++i) {
    int k = lane + i * 64;
    float hv = hr[k];
    float2 w = *(const float2*)(Wfc + 2 * k);
    s0 += hv * w.x;
    s1 += hv * w.y;
  }
#pragma unroll
  for (int off = 32; off > 0; off >>= 1) {
    s0 += __shfl_down(s0, off);
    s1 += __shfl_down(s1, off);
  }
  if (lane == 0) {
    s0 += bfc[0];
    s1 += bfc[1];
    float m = fmaxf(s0, s1);
    float lse = m + logf(expf(s0 - m) + expf(s1 - m));
    out[((size_t)row << 1) + 0] = s0 - lse;
    out[((size_t)row << 1) + 1] = s1 - lse;
  }
}

extern "C" void kernel_launch(void* const* d_in, const int* in_sizes, int n_in,
                              void* d_out, int out_size, void* d_ws, size_t ws_size,
                              hipStream_t stream)
{
  const int*   tokens = (const int*)d_in[0];
  const float* emb = (const float*)d_in[1];
  const float* W0i = (const float*)d_in[2];
  const float* b0i = (const float*)d_in[3];
  const float* W0f = (const float*)d_in[4];
  const float* b0f = (const float*)d_in[5];
  const float* W0g = (const float*)d_in[6];
  const float* b0g = (const float*)d_in[7];
  const float* W0o = (const float*)d_in[8];
  const float* b0o = (const float*)d_in[9];
  const float* W1i = (const float*)d_in[10];
  const float* b1i = (const float*)d_in[11];
  const float* W1f = (const float*)d_in[12];
  const float* b1f = (const float*)d_in[13];
  const float* W1g = (const float*)d_in[14];
  const float* b1g = (const float*)d_in[15];
  const float* W1o = (const float*)d_in[16];
  const float* b1o = (const float*)d_in[17];
  const float* Wfc = (const float*)d_in[18];
  const float* bfc = (const float*)d_in[19];
  float* out = (float*)d_out;

  float* ws = (float*)d_ws;
  float* x0 = ws;                               // 8192*512
  float* h0 = x0 + (size_t)8192 * 512;          // 8192*1024 (reused as h1)
  float* xp = h0 + (size_t)8192 * 1024;         // 8192*4096 (reused for both layers)
  unsigned* cnt = (unsigned*)(xp + (size_t)8192 * 4096);  // 8 u32

  zero_cnt_kernel<<<1, 64, 0, stream>>>(cnt);
  embed_kernel<<<4096, 256, 0, stream>>>(tokens, emb, x0);
  xproj_kernel<<<dim3(32, 64), 256, 0, stream>>>(x0, 512,  W0i, W0f, W0g, W0o,
                                                 b0i, b0f, b0g, b0o, xp);
  lstm_rec_kernel<<<256, 256, 0, stream>>>(xp, W0i, W0f, W0g, W0o, 512, h0, cnt);
  xproj_kernel<<<dim3(32, 64), 256, 0, stream>>>(h0, 1024, W1i, W1f, W1g, W1o,
                                                 b1i, b1f, b1g, b1o, xp);
  lstm_rec_kernel<<<256, 256, 0, stream>>>(xp, W1i, W1f, W1g, W1o, 1024, h0, cnt + 1);
  head_kernel<<<2048, 256, 0, stream>>>(h0, Wfc, bfc, out);
}

// Round 3
// 9527.274 us; speedup vs baseline: 4.2330x; 2.0212x over previous
//
#include <hip/hip_runtime.h>
#include <math.h>

// MultilayerLSTM: B=16, S=512, D_IN=512, D_H=1024, D_OUT=2, VOCAB=32000
// Round 2: MFMA recurrence. 64 persistent blocks x 256 threads (4 waves).
// Block owns 16 hidden cols; wave g computes gate g via mfma_f32_16x16x32_bf16
// (M=16 batches). W kept as persistent bf16 B-frags in VGPRs (128/thread).
// H exchanged in bf16 [t][b][k]; also stored f32 [b][t][k] for xproj/head.
// Grid barrier: agent-scope atomic + release/acquire fences (as round 0/1).

#define BB   16
#define SLEN 512
#define DIN  512
#define DH   1024

typedef __attribute__((ext_vector_type(8))) short short8;
typedef __attribute__((ext_vector_type(4))) float f32x4;

__device__ inline unsigned short f2bfbits(float x) {
  union { float f; unsigned u; } v; v.f = x;
  unsigned r = v.u + 0x7FFF + ((v.u >> 16) & 1);  // RNE
  return (unsigned short)(r >> 16);
}

// ---------------- zero counters ----------------
__global__ void zero_cnt_kernel(unsigned* cnt) {
  if (threadIdx.x < 8) cnt[threadIdx.x] = 0;
}

// ---------------- embedding gather ----------------
__global__ __launch_bounds__(256) void embed_kernel(const int* __restrict__ tokens,
                                                    const float* __restrict__ emb,
                                                    float* __restrict__ x0) {
  int idx = blockIdx.x * 256 + threadIdx.x;  // over 8192*128 float4s
  int r = idx >> 7, d4 = idx & 127;
  int tok = tokens[r];
  const float4* src = (const float4*)emb + (((size_t)tok) << 7) + d4;
  ((float4*)x0)[(((size_t)r) << 7) + d4] = *src;
}

// ---------------- xproj GEMM: C[M][4096] = A[M][K] @ W_g[K][1024] + b_g ----------------
__global__ __launch_bounds__(256) void xproj_kernel(
    const float* __restrict__ A, int K,
    const float* __restrict__ Wi, const float* __restrict__ Wf,
    const float* __restrict__ Wg, const float* __restrict__ Wo,
    const float* __restrict__ bi, const float* __restrict__ bf,
    const float* __restrict__ bg, const float* __restrict__ bo,
    float* __restrict__ Cout)
{
  __shared__ float As[8][128];
  __shared__ float Bs[8][128];
  const int tid = threadIdx.x;
  const int bn = blockIdx.x;   // 0..31
  const int bm = blockIdx.y;   // 0..63
  const int m0 = bm * 128;
  const int n0 = bn * 128;
  const int g = n0 >> 10;
  const float* W    = (g == 0) ? Wi : (g == 1) ? Wf : (g == 2) ? Wg : Wo;
  const float* bias = (g == 0) ? bi : (g == 1) ? bf : (g == 2) ? bg : bo;
  const int col0 = n0 & 1023;
  const int tx = tid & 15, ty = tid >> 4;
  const int lr = tid >> 1, lh = tid & 1;          // A-tile loader
  const int lk = tid >> 5, ln = (tid & 31) << 2;  // B-tile loader

  float acc[8][8];
#pragma unroll
  for (int i = 0; i < 8; ++i)
#pragma unroll
    for (int j = 0; j < 8; ++j) acc[i][j] = 0.f;

  for (int k0 = 0; k0 < K; k0 += 8) {
    float4 av = *(const float4*)(A + (size_t)(m0 + lr) * K + k0 + lh * 4);
    float4 bv = *(const float4*)(W + (size_t)(k0 + lk) * 1024 + col0 + ln);
    As[lh * 4 + 0][lr] = av.x;
    As[lh * 4 + 1][lr] = av.y;
    As[lh * 4 + 2][lr] = av.z;
    As[lh * 4 + 3][lr] = av.w;
    *(float4*)&Bs[lk][ln] = bv;
    __syncthreads();
#pragma unroll
    for (int p = 0; p < 8; ++p) {
      float a[8], b[8];
      *(float4*)&a[0] = *(const float4*)&As[p][ty * 8];
      *(float4*)&a[4] = *(const float4*)&As[p][ty * 8 + 4];
      *(float4*)&b[0] = *(const float4*)&Bs[p][tx * 4];
      *(float4*)&b[4] = *(const float4*)&Bs[p][64 + tx * 4];
#pragma unroll
      for (int i = 0; i < 8; ++i)
#pragma unroll
        for (int j = 0; j < 8; ++j) acc[i][j] += a[i] * b[j];
    }
    __syncthreads();
  }
  float4 bA = *(const float4*)(bias + col0 + tx * 4);
  float4 bB = *(const float4*)(bias + col0 + 64 + tx * 4);
#pragma unroll
  for (int i = 0; i < 8; ++i) {
    int m = m0 + ty * 8 + i;
    float* crow = Cout + (((size_t)m) << 12) + n0;
    float4 o1 = make_float4(acc[i][0] + bA.x, acc[i][1] + bA.y, acc[i][2] + bA.z, acc[i][3] + bA.w);
    float4 o2 = make_float4(acc[i][4] + bB.x, acc[i][5] + bB.y, acc[i][6] + bB.z, acc[i][7] + bB.w);
    *(float4*)(crow + tx * 4) = o1;
    *(float4*)(crow + 64 + tx * 4) = o2;
  }
}

// ---------------- MFMA persistent LSTM recurrence ----------------
// 64 blocks x 256 threads. Block owns hidden cols c0 = blockIdx.x*16 .. +15.
// Wave g (tid>>6) = gate g. Per step per wave: 32x mfma_f32_16x16x32_bf16
// (A = H(t-1) [16 x 1024] bf16 loaded from global/cache; B = persistent
// W-frags in VGPRs; C init = xp). Cell update: thread (b,c) owns Creg.
__global__ __launch_bounds__(256, 1) void lstm_rec_mfma(
    const float* __restrict__ xp,
    const float* __restrict__ Wi, const float* __restrict__ Wf,
    const float* __restrict__ Wg, const float* __restrict__ Wo,
    int D,
    short* __restrict__ hb16,        // bf16 bits [t][b][1024]
    float* __restrict__ hf32,        // f32 [b][t][1024]
    unsigned* __restrict__ cnt)
{
  __shared__ float Pre[4][16][16];
  const int tid  = threadIdx.x;
  const int wv   = tid >> 6;         // gate
  const int lane = tid & 63;
  const int q    = lane >> 4;        // quad
  const int n    = lane & 15;        // output col within tile
  const int c0   = blockIdx.x << 4;
  const float* Wsel = (wv == 0) ? Wi : (wv == 1) ? Wf : (wv == 2) ? Wg : Wo;

  // persistent B-frags: wfrag[kk] holds W[D + kk*32 + q*8 + j][c0+n], j=0..7
  short8 wfrag[32];
#pragma unroll
  for (int kk = 0; kk < 32; ++kk) {
#pragma unroll
    for (int j = 0; j < 8; ++j) {
      float w = Wsel[(size_t)(D + kk * 32 + q * 8 + j) * 1024 + c0 + n];
      wfrag[kk][j] = (short)f2bfbits(w);
    }
  }

  const int cb = tid >> 4, cc = tid & 15;  // cell-update mapping
  float Creg = 0.f;

  for (int t = 0; t < SLEN; ++t) {
    // acc init from xp (bias folded by xproj): rows b = q*4 + r
    f32x4 acc;
#pragma unroll
    for (int r = 0; r < 4; ++r)
      acc[r] = xp[(((size_t)((q * 4 + r) * SLEN + t)) << 12) + (wv << 10) + c0 + n];

    if (t > 0) {
      const short* hb = hb16 + (((size_t)(t - 1)) << 14);  // [b][k] bf16
#pragma unroll
      for (int kk = 0; kk < 32; ++kk) {
        short8 af = *(const short8*)(hb + n * 1024 + kk * 32 + q * 8);
        acc = __builtin_amdgcn_mfma_f32_16x16x32_bf16(af, wfrag[kk], acc, 0, 0, 0);
      }
    }

    // exchange preacts via LDS
#pragma unroll
    for (int r = 0; r < 4; ++r) Pre[wv][q * 4 + r][n] = acc[r];
    __syncthreads();

    // cell update: thread (cb, cc)
    float pI = Pre[0][cb][cc];
    float pF = Pre[1][cb][cc];
    float pG = Pre[2][cb][cc];
    float pO = Pre[3][cb][cc];
    float gI = 1.f / (1.f + __expf(-pI));
    float gF = 1.f / (1.f + __expf(-pF));
    float gG = tanhf(pG);
    float gO = 1.f / (1.f + __expf(-pO));
    Creg = gF * Creg + gI * gG;
    float h = gO * tanhf(Creg);

    // f32 store [b][t][k] for xproj(l1)/head
    hf32[(((size_t)(cb * SLEN + t)) << 10) + c0 + cc] = h;
    // bf16 store [t][b][k]: pack pairs via shfl (tid^1 is same wave)
    unsigned mybits = (unsigned)f2bfbits(h);
    unsigned nbbits = (unsigned)__shfl_xor((int)mybits, 1, 64);
    if ((cc & 1) == 0) {
      unsigned pk = mybits | (nbbits << 16);
      *(unsigned*)(hb16 + (((size_t)(t * 16 + cb)) << 10) + c0 + cc) = pk;
    }
    __syncthreads();

    // grid barrier (64 blocks); kernel boundary flushes after last step
    if (t + 1 < SLEN) {
      if (tid == 0) {
        __builtin_amdgcn_fence(__ATOMIC_RELEASE, "agent");
        __hip_atomic_fetch_add(cnt, 1u, __ATOMIC_RELAXED, __HIP_MEMORY_SCOPE_AGENT);
        const unsigned target = 64u * (unsigned)(t + 1);
        while (__hip_atomic_load(cnt, __ATOMIC_RELAXED, __HIP_MEMORY_SCOPE_AGENT) < target) {
          __builtin_amdgcn_s_sleep(1);
        }
        __builtin_amdgcn_fence(__ATOMIC_ACQUIRE, "agent");
      }
      __syncthreads();
    }
  }
}

// ---------------- FC head + log_softmax (D_OUT=2) ----------------
__global__ __launch_bounds__(256) void head_kernel(const float* __restrict__ h,
                                                   const float* __restrict__ Wfc,
                                                   const float* __restrict__ bfc,
                                                   float* __restrict__ out)
{
  const int lane = threadIdx.x & 63;
  const int row = blockIdx.x * 4 + (threadIdx.x >> 6);
  const float* hr = h + (((size_t)row) << 10);
  float s0 = 0.f, s1 = 0.f;
#pragma unroll
  for (int i = 0; i < 16; ++i) {
    int k = lane + i * 64;
    float hv = hr[k];
    float2 w = *(const float2*)(Wfc + 2 * k);
    s0 += hv * w.x;
    s1 += hv * w.y;
  }
#pragma unroll
  for (int off = 32; off > 0; off >>= 1) {
    s0 += __shfl_down(s0, off);
    s1 += __shfl_down(s1, off);
  }
  if (lane == 0) {
    s0 += bfc[0];
    s1 += bfc[1];
    float m = fmaxf(s0, s1);
    float lse = m + logf(expf(s0 - m) + expf(s1 - m));
    out[((size_t)row << 1) + 0] = s0 - lse;
    out[((size_t)row << 1) + 1] = s1 - lse;
  }
}

extern "C" void kernel_launch(void* const* d_in, const int* in_sizes, int n_in,
                              void* d_out, int out_size, void* d_ws, size_t ws_size,
                              hipStream_t stream)
{
  const int*   tokens = (const int*)d_in[0];
  const float* emb = (const float*)d_in[1];
  const float* W0i = (const float*)d_in[2];
  const float* b0i = (const float*)d_in[3];
  const float* W0f = (const float*)d_in[4];
  const float* b0f = (const float*)d_in[5];
  const float* W0g = (const float*)d_in[6];
  const float* b0g = (const float*)d_in[7];
  const float* W0o = (const float*)d_in[8];
  const float* b0o = (const float*)d_in[9];
  const float* W1i = (const float*)d_in[10];
  const float* b1i = (const float*)d_in[11];
  const float* W1f = (const float*)d_in[12];
  const float* b1f = (const float*)d_in[13];
  const float* W1g = (const float*)d_in[14];
  const float* b1g = (const float*)d_in[15];
  const float* W1o = (const float*)d_in[16];
  const float* b1o = (const float*)d_in[17];
  const float* Wfc = (const float*)d_in[18];
  const float* bfc = (const float*)d_in[19];
  float* out = (float*)d_out;

  float* ws = (float*)d_ws;
  float* x0 = ws;                               // 8192*512 f32; later aliased as bf16 h [t][b][1024]
  float* h0 = x0 + (size_t)8192 * 512;          // 8192*1024 f32 [b][t][k] (both layers)
  float* xp = h0 + (size_t)8192 * 1024;         // 8192*4096 f32 (both layers)
  unsigned* cnt = (unsigned*)(xp + (size_t)8192 * 4096);  // 8 u32
  short* hb16 = (short*)x0;                     // 512*16*1024 bf16 = 16 MB (aliases x0)

  zero_cnt_kernel<<<1, 64, 0, stream>>>(cnt);
  embed_kernel<<<4096, 256, 0, stream>>>(tokens, emb, x0);
  xproj_kernel<<<dim3(32, 64), 256, 0, stream>>>(x0, 512,  W0i, W0f, W0g, W0o,
                                                 b0i, b0f, b0g, b0o, xp);
  // rec(l0): writes hb16 over x0 (x0 fully consumed by xproj above)
  lstm_rec_mfma<<<64, 256, 0, stream>>>(xp, W0i, W0f, W0g, W0o, 512, hb16, h0, cnt);
  xproj_kernel<<<dim3(32, 64), 256, 0, stream>>>(h0, 1024, W1i, W1f, W1g, W1o,
                                                 b1i, b1f, b1g, b1o, xp);
  lstm_rec_mfma<<<64, 256, 0, stream>>>(xp, W1i, W1f, W1g, W1o, 1024, hb16, h0, cnt + 1);
  head_kernel<<<2048, 256, 0, stream>>>(h0, Wfc, bfc, out);
}